// Round 4
// baseline (188.090 us; speedup 1.0000x reference)
//
#include <hip/hip_runtime.h>
#include <hip/hip_bf16.h>

typedef __attribute__((ext_vector_type(8))) short bf16x8;
typedef __attribute__((ext_vector_type(4))) float f32x4;

#define MARGIN 0.3f
#define BIGF 3.0e38f

__device__ __forceinline__ void gl2lds16(const void* g, void* l) {
    __builtin_amdgcn_global_load_lds(
        (const __attribute__((address_space(1))) void*)g,
        (__attribute__((address_space(3))) void*)l,
        16, 0, 0);
}

// Raw barriers (bypass __syncthreads' vmcnt(0) drain — m139 pattern).
// BAR_W6: all but the newest 6 vmem ops (the just-issued next-tile stage)
// must have landed; lgkmcnt(0) covers prologue/epilogue ds_writes.
#define BAR_W6() asm volatile("s_waitcnt vmcnt(6) lgkmcnt(0)\n\ts_barrier" ::: "memory")
#define BAR_W0() asm volatile("s_waitcnt vmcnt(0) lgkmcnt(0)\n\ts_barrier" ::: "memory")
#define BAR_END() asm volatile("s_waitcnt lgkmcnt(0)\n\ts_barrier" ::: "memory")

// Wave-per-row convert: fp32 -> bf16 cast, fp32 row norm (of the
// bf16-rounded values, consistent with MFMA dots), init ap/an/cnt.
// 4 rows per 256-thread block, shuffle-only reduce (no __syncthreads).
__global__ __launch_bounds__(256) void convert_norm_kernel(
    const float* __restrict__ X, __hip_bfloat16* __restrict__ Xb,
    float* __restrict__ nrm, unsigned* __restrict__ ap,
    unsigned* __restrict__ an, unsigned* __restrict__ cnt, int K) {
    const int wave = threadIdx.x >> 6, lane = threadIdx.x & 63;
    const int row = blockIdx.x * 4 + wave;
    const float* xr = X + (size_t)row * K;
    __hip_bfloat16* xbr = Xb + (size_t)row * K;
    float s = 0.0f;
    for (int c = lane * 4; c < K; c += 64 * 4) {
        float4 v = *(const float4*)(xr + c);
        union { __hip_bfloat16 h[4]; uint2 u; } p;
        p.h[0] = __float2bfloat16(v.x);
        p.h[1] = __float2bfloat16(v.y);
        p.h[2] = __float2bfloat16(v.z);
        p.h[3] = __float2bfloat16(v.w);
        *(uint2*)(xbr + c) = p.u;
        float f0 = __bfloat162float(p.h[0]);
        float f1 = __bfloat162float(p.h[1]);
        float f2 = __bfloat162float(p.h[2]);
        float f3 = __bfloat162float(p.h[3]);
        s += f0 * f0 + f1 * f1 + f2 * f2 + f3 * f3;
    }
    for (int off = 32; off > 0; off >>= 1) s += __shfl_xor(s, off, 64);
    if (lane == 0) {
        nrm[row] = s;
        ap[row] = 0u;           // dist_ap >= 0 always (self is a positive)
        an[row] = 0x7F800000u;  // +inf
        if (row == 0) *cnt = 0u;
    }
}

// Upper-triangle 64x128 tiles (1056 blocks at N=4096), BK=64, XOR-swizzled
// LDS (0 conflicts, verified R2/R3), DOUBLE-BUFFERED with fine-grained
// vmcnt: stage(kt+1) issues before waiting on stage(kt), so global->LDS
// latency hides behind the compute phase instead of being drained at a
// vmcnt(0) barrier every iteration (the R3 serialization).
// Epilogue reduces rows (cross-wave) and cols (wave-local) into global
// ap/an via monotone uint atomics; LAST block computes the loss.
__global__ __launch_bounds__(256) void gemm_reduce_kernel(
    const __hip_bfloat16* __restrict__ Xb, const float* __restrict__ nrm,
    const int* __restrict__ Y, unsigned* __restrict__ ap,
    unsigned* __restrict__ an, unsigned* __restrict__ cnt,
    float* __restrict__ out, int N, int K) {
    __shared__ __align__(16) __hip_bfloat16 sA[2 * 64 * 64];   // 16KB, 2 bufs
    __shared__ __align__(16) __hip_bfloat16 sB[2 * 128 * 64];  // 32KB, 2 bufs
    __shared__ int sYr[64], sYc[128];
    __shared__ float sNr[64], sNc[128];
    __shared__ float redmax[4][64], redmin[4][64];  // row-side, per wave
    __shared__ float credmax[128], credmin[128];    // col-side
    __shared__ unsigned s_done;

    const int tid = threadIdx.x;
    const int wave = tid >> 6;
    const int lane = tid & 63;
    const int q = lane >> 4;   // quad within wave
    const int lc = lane & 15;  // col within 16x16 subtile

    // Decode (col-block j, row-block r): blocks for col j are j(j+1)..(j+1)(j+2).
    int j = 0;
    {
        const int b = blockIdx.x;
        while ((j + 1) * (j + 2) <= b) j++;
    }
    const int r = blockIdx.x - j * (j + 1);  // 0..2j+1
    const int rowBase = r * 64;
    const int colBase = j * 128;

    if (tid < 64) {
        sYr[tid] = Y[rowBase + tid];
        sNr[tid] = nrm[rowBase + tid];
    } else if (tid < 192) {
        int t = tid - 64;
        sYc[t] = Y[colBase + t];
        sNc[t] = nrm[colBase + t];
    }

    f32x4 acc[4][2];
#pragma unroll
    for (int i = 0; i < 4; i++)
#pragma unroll
        for (int jj = 0; jj < 2; jj++) acc[i][jj] = (f32x4){0.f, 0.f, 0.f, 0.f};

    // Staging: lane l -> LDS row l>>3 (of an 8-row group), physical 16B
    // chunk l&7; lane fetches LOGICAL chunk (l&7)^(l>>3) (XOR swizzle).
    const int rsub = lane >> 3;
    const int jchunk = (lane & 7) ^ rsub;
    const char* gA = (const char*)(Xb + (size_t)(rowBase + wave * 16 + rsub) * K) + jchunk * 16;
    const char* gB = (const char*)(Xb + (size_t)(colBase + wave * 32 + rsub) * K) + jchunk * 16;
    char* lA = (char*)sA + wave * 2048;  // 16 rows * 128B (buf 0)
    char* lB = (char*)sB + wave * 4096;  // 32 rows * 128B (buf 0)
    const size_t g8 = (size_t)8 * K * 2;

    // Fragment read offsets: row m = subtile*16 + lc; kk=0 logical chunk q,
    // kk=1 logical chunk 4+q; physical = logical ^ (lc&7).
    const int xo0 = ((q ^ (lc & 7)) * 16);
    const int xo1 = (((4 + q) ^ (lc & 7)) * 16);
    const int arow = lc * 128;               // + si*2048 (+ buf*8192)
    const int brow = (wave * 32 + lc) * 128; // + sj*2048 (+ buf*16384)

    const int nit = K >> 6;  // BK=64

    // Prologue: stage tile 0 into buffer 0.
    {
        gl2lds16(gA, lA);
        gl2lds16(gA + g8, lA + 1024);
        gl2lds16(gB, lB);
        gl2lds16(gB + g8, lB + 1024);
        gl2lds16(gB + 2 * g8, lB + 2048);
        gl2lds16(gB + 3 * g8, lB + 3072);
    }

    for (int kt = 0; kt < nit; kt++) {
        if (kt + 1 < nit) {
            // Stage tile kt+1 into the other buffer, then wait for tile kt
            // (all but the 6 just-issued loads) and sync.
            const size_t go = (size_t)(kt + 1) * 128;  // 64 k-elems * 2B
            const int nb = (kt + 1) & 1;
            char* dA = lA + nb * 8192;
            char* dB = lB + nb * 16384;
            gl2lds16(gA + go, dA);
            gl2lds16(gA + go + g8, dA + 1024);
            gl2lds16(gB + go, dB);
            gl2lds16(gB + go + g8, dB + 1024);
            gl2lds16(gB + go + 2 * g8, dB + 2048);
            gl2lds16(gB + go + 3 * g8, dB + 3072);
            BAR_W6();
        } else {
            BAR_W0();
        }

        const int aoff = (kt & 1) * 8192;
        const int boff = (kt & 1) * 16384;
#pragma unroll
        for (int kk = 0; kk < 2; kk++) {
            const int xo = kk ? xo1 : xo0;
            bf16x8 af[4], bfr[2];
#pragma unroll
            for (int b = 0; b < 4; b++)
                af[b] = *(const bf16x8*)((const char*)sA + aoff + arow + b * 2048 + xo);
#pragma unroll
            for (int b = 0; b < 2; b++)
                bfr[b] = *(const bf16x8*)((const char*)sB + boff + brow + b * 2048 + xo);
#pragma unroll
            for (int si = 0; si < 4; si++)
#pragma unroll
                for (int sj = 0; sj < 2; sj++)
                    acc[si][sj] = __builtin_amdgcn_mfma_f32_16x16x32_bf16(
                        af[si], bfr[sj], acc[si][sj], 0, 0, 0);
        }
        // Protect buf[kt&1] from being restaged (iter kt+1) while laggard
        // waves still read it. No vmem drain here — that's the point.
        BAR_END();
    }

    // Epilogue. C/D layout: col = lc, row = q*4 + reg (within subtile).
    float rmx[4][4], rmn[4][4];
    float cmx[2], cmn[2];
#pragma unroll
    for (int i = 0; i < 4; i++)
#pragma unroll
        for (int rr = 0; rr < 4; rr++) { rmx[i][rr] = -1.0f; rmn[i][rr] = BIGF; }
    cmx[0] = cmx[1] = -1.0f; cmn[0] = cmn[1] = BIGF;

#pragma unroll
    for (int sj = 0; sj < 2; sj++) {
        const int ct = wave * 32 + sj * 16 + lc;
        const int yc = sYc[ct];
        const float nc = sNc[ct];
#pragma unroll
        for (int si = 0; si < 4; si++) {
            const int rbase = si * 16 + q * 4;
#pragma unroll
            for (int rr = 0; rr < 4; rr++) {
                const int rt = rbase + rr;
                float d2 = sNr[rt] + nc - 2.0f * acc[si][sj][rr];
                float d = sqrtf(fmaxf(d2, 0.0f));
                bool same = (sYr[rt] == yc);
                float dp = same ? d : -1.0f;
                float dn = same ? BIGF : d;
                rmx[si][rr] = fmaxf(rmx[si][rr], dp);
                rmn[si][rr] = fminf(rmn[si][rr], dn);
                cmx[sj] = fmaxf(cmx[sj], dp);
                cmn[sj] = fminf(cmn[sj], dn);
            }
        }
    }

    // Row-side: butterfly across the 16 lanes of a quad (same row, 16 cols).
#pragma unroll
    for (int si = 0; si < 4; si++)
#pragma unroll
        for (int rr = 0; rr < 4; rr++) {
            float mx = rmx[si][rr], mn = rmn[si][rr];
            for (int off = 1; off < 16; off <<= 1) {
                mx = fmaxf(mx, __shfl_xor(mx, off, 64));
                mn = fminf(mn, __shfl_xor(mn, off, 64));
            }
            if (lc == 0) {
                redmax[wave][si * 16 + q * 4 + rr] = mx;
                redmin[wave][si * 16 + q * 4 + rr] = mn;
            }
        }

    // Col-side: reduce across quads (different rows, same col).
#pragma unroll
    for (int sj = 0; sj < 2; sj++) {
        float mx = cmx[sj], mn = cmn[sj];
        mx = fmaxf(mx, __shfl_xor(mx, 16, 64));
        mn = fminf(mn, __shfl_xor(mn, 16, 64));
        mx = fmaxf(mx, __shfl_xor(mx, 32, 64));
        mn = fminf(mn, __shfl_xor(mn, 32, 64));
        if (q == 0) {
            credmax[wave * 32 + sj * 16 + lc] = mx;
            credmin[wave * 32 + sj * 16 + lc] = mn;
        }
    }
    __syncthreads();

    // Non-negative floats: uint cmp == float cmp. Clamp max to 0 (true
    // dist_ap >= 0 via the diagonal self-pair).
    if (tid < 64) {
        float mx = fmaxf(fmaxf(redmax[0][tid], redmax[1][tid]),
                         fmaxf(redmax[2][tid], redmax[3][tid]));
        float mn = fminf(fminf(redmin[0][tid], redmin[1][tid]),
                         fminf(redmin[2][tid], redmin[3][tid]));
        atomicMax(&ap[rowBase + tid], __float_as_uint(fmaxf(mx, 0.0f)));
        atomicMin(&an[rowBase + tid], __float_as_uint(mn));
    } else if (tid < 192) {
        int c = tid - 64;
        atomicMax(&ap[colBase + c], __float_as_uint(fmaxf(credmax[c], 0.0f)));
        atomicMin(&an[colBase + c], __float_as_uint(credmin[c]));
    }

    // Last block computes the loss (release fence before counter increment;
    // acquire fence + agent-scope atomic loads in the last block).
    __syncthreads();
    if (tid == 0) {
        __threadfence();
        s_done = atomicAdd(cnt, 1u);
    }
    __syncthreads();
    if (s_done == gridDim.x - 1) {
        __threadfence();
        float s = 0.0f;
        for (int i = tid; i < N; i += 256) {
            unsigned ua = __hip_atomic_load(&ap[i], __ATOMIC_RELAXED,
                                            __HIP_MEMORY_SCOPE_AGENT);
            unsigned ub = __hip_atomic_load(&an[i], __ATOMIC_RELAXED,
                                            __HIP_MEMORY_SCOPE_AGENT);
            s += fmaxf(__uint_as_float(ua) - __uint_as_float(ub) + MARGIN, 0.0f);
        }
        for (int off = 32; off > 0; off >>= 1) s += __shfl_down(s, off, 64);
        if ((tid & 63) == 0) credmax[tid >> 6] = s;  // reuse as scratch
        __syncthreads();
        if (tid == 0)
            out[0] = (credmax[0] + credmax[1] + credmax[2] + credmax[3]) / (float)N;
    }
}

extern "C" void kernel_launch(void* const* d_in, const int* in_sizes, int n_in,
                              void* d_out, int out_size, void* d_ws, size_t ws_size,
                              hipStream_t stream) {
    const float* X = (const float*)d_in[0];
    const int* Y = (const int*)d_in[1];
    float* out = (float*)d_out;
    const int N = in_sizes[1];          // 4096
    const int K = in_sizes[0] / N;      // 2048

    char* ws = (char*)d_ws;
    __hip_bfloat16* Xb = (__hip_bfloat16*)ws;                       // N*K*2 bytes
    float* nrm = (float*)(ws + (size_t)N * K * sizeof(__hip_bfloat16));
    unsigned* ap = (unsigned*)((char*)nrm + (size_t)N * 4);
    unsigned* an = (unsigned*)((char*)ap + (size_t)N * 4);
    unsigned* cnt = (unsigned*)((char*)an + (size_t)N * 4);

    convert_norm_kernel<<<N / 4, 256, 0, stream>>>(X, Xb, nrm, ap, an, cnt, K);
    const int NB = N / 128;
    const int nblocks = NB * (NB + 1);  // 64x128 tiles covering the triangle
    gemm_reduce_kernel<<<nblocks, 256, 0, stream>>>(Xb, nrm, Y, ap, an, cnt,
                                                    out, N, K);
}